// Round 20
// baseline (20.954 us; speedup 1.0000x reference)
//
#include <hip/hip_runtime.h>

#define N_QUBITS 5
#define DIM 32

// ---------- verified perm machinery (rounds 1/2/7-19) ----------
__host__ __device__ constexpr int cnot_apply(int i, int ctrl, int tgt) {
    const int pc = N_QUBITS - 1 - ctrl;
    const int pt = N_QUBITS - 1 - tgt;
    return i ^ (((i >> pc) & 1) << pt);
}
__host__ __device__ constexpr int layer_perm(int i, int r) {
    int idx = i;
    for (int q = N_QUBITS - 1; q >= 0; --q)
        idx = cnot_apply(idx, q, (q + r) % N_QUBITS);
    return idx;
}
__host__ __device__ constexpr int invP(int p, int r) {
    for (int l = 0; l < 32; ++l) if (layer_perm(l, r) == p) return l;
    return 0;
}
__host__ __device__ constexpr int pc5(int m) {
    int c = 0;
    for (int b = 0; b < 5; ++b) c += (m >> b) & 1;
    return c;
}
__host__ __device__ constexpr int pow3(int n) {
    int r = 1;
    for (int i = 0; i < n; ++i) r *= 3;
    return r;
}
__host__ __device__ constexpr int Mmask(int q) {
    int m = 0;
    for (int b = 0; b < 5; ++b)
        m |= ((invP(1 << b, 2) >> (4 - q)) & 1) << b;
    return m;
}
__host__ __device__ constexpr int NC(int q) { return pow3(pc5(Mmask(q))); }

// One Pauli string (r19 PASS-verified machinery, unchanged)
struct SInfo {
    int sign;
    int nf;
    int fidx[5];
    int k;
    int eb[5];
    int et[5];
};

__host__ __device__ constexpr SInfo make_sinfo(int Q, int C) {
    SInfo s{};
    const int M = Mmask(Q);
    int x = 0, z = 0, c = C;
    s.nf = 0;
    for (int b = 0; b < 5; ++b) {
        if ((M >> b) & 1) {
            const int t = c % 3; c /= 3;
            s.fidx[s.nf] = b * 3 + t;
            s.nf++;
            if (t == 0)      z |= 1 << b;
            else if (t == 1) x |= 1 << b;
            else           { x |= 1 << b; z |= 1 << b; }
        }
    }
    const int xp = layer_perm(x, 1);
    int zp = 0;
    for (int b = 0; b < 5; ++b)
        zp |= (pc5(z & invP(1 << b, 1)) & 1) << b;
    const int d  = pc5(x & z) - pc5(xp & zp);
    const int dm = ((d % 4) + 4) % 4;
    s.sign = (dm == 0) ? 1 : -1;
    s.k = 0;
    for (int b = 0; b < 5; ++b) {
        const int tx = (xp >> b) & 1, tz = (zp >> b) & 1;
        if (tx | tz) {
            s.eb[s.k] = b;
            s.et[s.k] = tx ? (tz ? 2 : 1) : 0;
            s.k++;
        }
    }
    return s;
}

#define EPICK(T, B) ((T) == 0 ? EZ[B] : ((T) == 1 ? EX[B] : EY[B]))

template<int Q, int C>
__device__ __forceinline__ float sterm(const float (&a)[15],
        const float (&EZ)[5], const float (&EX)[5], const float (&EY)[5]) {
    constexpr SInfo s = make_sinfo(Q, C);
    float cf = a[s.fidx[0]];
    if constexpr (s.nf > 1) cf *= a[s.fidx[1]];
    if constexpr (s.nf > 2) cf *= a[s.fidx[2]];
    if constexpr (s.nf > 3) cf *= a[s.fidx[3]];
    if constexpr (s.nf > 4) cf *= a[s.fidx[4]];
    float e = EPICK(s.et[0], s.eb[0]);
    if constexpr (s.k > 1) e *= EPICK(s.et[1], s.eb[1]);
    if constexpr (s.k > 2) e *= EPICK(s.et[2], s.eb[2]);
    if constexpr (s.k > 3) e *= EPICK(s.et[3], s.eb[3]);
    if constexpr (s.k > 4) e *= EPICK(s.et[4], s.eb[4]);
    if constexpr (s.sign < 0) return e * (-cf);
    else                      return e * cf;
}

template<int Q, int C>
struct SSum {
    static __device__ __forceinline__ float go(const float (&a)[15],
            const float (&EZ)[5], const float (&EX)[5], const float (&EY)[5]) {
        return SSum<Q, C - 1>::go(a, EZ, EX, EY) + sterm<Q, C>(a, EZ, EX, EY);
    }
};
template<int Q>
struct SSum<Q, 0> {
    static __device__ __forceinline__ float go(const float (&a)[15],
            const float (&EZ)[5], const float (&EX)[5], const float (&EY)[5]) {
        return sterm<Q, 0>(a, EZ, EX, EY);
    }
};

// Heisenberg picture, 1 batch/thread scalar: 262144 threads = 4096 waves
// = 4 waves/SIMD (r19's 2-batch packing capped the GRID at 2 waves/SIMD).
// Live set ~50-60 VGPR: no big arrays, demotion impossible.
__global__ __launch_bounds__(256, 4) void vqc_kernel(
    const float* __restrict__ x,      // (B, 5)
    const float* __restrict__ w,      // (2, 5, 3)
    const float* __restrict__ fc_w,   // (8, 5)
    const float* __restrict__ fc_b,   // (8,)
    float* __restrict__ out,          // (B, 8)
    int Btot)
{
    __shared__ float s_g0[N_QUBITS][8];   // layer 0: full Rot coeffs (r15-verified)
    __shared__ float s_a[15];             // Heisenberg coefs (r19-verified)
    __shared__ float s_fc_w[40];
    __shared__ float s_fc_b[8];

    const int t = threadIdx.x;
    if (t < N_QUBITS) {
        const float phi = w[t * 3 + 0];
        const float th  = w[t * 3 + 1];
        const float om  = w[t * 3 + 2];
        float s, c;   sincosf(0.5f * th, &s, &c);
        float sp, cp; sincosf(0.5f * (phi + om), &sp, &cp);
        float sm, cm; sincosf(0.5f * (phi - om), &sm, &cm);
        s_g0[t][0] =  cp * c;  s_g0[t][1] = -sp * c;
        s_g0[t][2] = -cm * s;  s_g0[t][3] = -sm * s;
        s_g0[t][4] =  cm * s;  s_g0[t][5] = -sm * s;
        s_g0[t][6] =  cp * c;  s_g0[t][7] =  sp * c;
    } else if (t >= 8 && t < 13) {
        const int q = t - 8;
        const float phi = w[(N_QUBITS + q) * 3 + 0];
        const float th  = w[(N_QUBITS + q) * 3 + 1];
        float sth, cth; sincosf(th,  &sth, &cth);
        float sph, cph; sincosf(phi, &sph, &cph);
        const int b = 4 - q;
        s_a[b * 3 + 0] = cth;
        s_a[b * 3 + 1] = -sth * cph;
        s_a[b * 3 + 2] =  sth * sph;
    } else if (t >= 64 && t < 104) {
        s_fc_w[t - 64] = fc_w[t - 64];
    } else if (t >= 104 && t < 112) {
        s_fc_b[t - 104] = fc_b[t - 104];
    }
    __syncthreads();

    const int b = blockIdx.x * 256 + t;
    if (b >= Btot) return;

    const float* xp = x + (size_t)b * 5;

    // ---- per-qubit v = Rot0_q RX(x_q)|0> and Pauli expectations (scalar) ----
    float EZ[5], EX[5], EY[5];
#pragma unroll
    for (int q = 0; q < N_QUBITS; ++q) {
        float s, c;
        __sincosf(0.5f * xp[q], &s, &c);
        const float v0re = s_g0[q][0] * c + s_g0[q][3] * s;
        const float v0im = s_g0[q][1] * c - s_g0[q][2] * s;
        const float v1re = s_g0[q][4] * c + s_g0[q][7] * s;
        const float v1im = s_g0[q][5] * c - s_g0[q][6] * s;
        const int bb = 4 - q;
        EZ[bb] = v0re * v0re + v0im * v0im - v1re * v1re - v1im * v1im;
        EX[bb] = 2.f * (v0re * v1re + v0im * v1im);
        EY[bb] = 2.f * (v0re * v1im - v0im * v1re);
    }

    float a[15];
#pragma unroll
    for (int i = 0; i < 15; ++i) a[i] = s_a[i];

    // ---- expvals: compile-time Pauli-string sums (r19-verified) ----
    float ev[N_QUBITS];
    ev[0] = SSum<0, NC(0) - 1>::go(a, EZ, EX, EY);
    ev[1] = SSum<1, NC(1) - 1>::go(a, EZ, EX, EY);
    ev[2] = SSum<2, NC(2) - 1>::go(a, EZ, EX, EY);
    ev[3] = SSum<3, NC(3) - 1>::go(a, EZ, EX, EY);
    ev[4] = SSum<4, NC(4) - 1>::go(a, EZ, EX, EY);

    // ---- FC + coalesced stores ----
    float o[8];
#pragma unroll
    for (int j = 0; j < 8; ++j) {
        float acc = s_fc_b[j];
#pragma unroll
        for (int q = 0; q < 5; ++q) acc += ev[q] * s_fc_w[j * 5 + q];
        o[j] = acc;
    }
    float4* op = (float4*)(out + (size_t)b * 8);
    op[0] = make_float4(o[0], o[1], o[2], o[3]);
    op[1] = make_float4(o[4], o[5], o[6], o[7]);
}

extern "C" void kernel_launch(void* const* d_in, const int* in_sizes, int n_in,
                              void* d_out, int out_size, void* d_ws, size_t ws_size,
                              hipStream_t stream) {
    const float* x    = (const float*)d_in[0];
    const float* w    = (const float*)d_in[1];
    const float* fc_w = (const float*)d_in[2];
    const float* fc_b = (const float*)d_in[3];
    float* out = (float*)d_out;

    const int Btot = in_sizes[0] / N_QUBITS;   // 262144
    const int grid = (Btot + 255) / 256;       // 1024 blocks = 4096 waves = 4/SIMD
    hipLaunchKernelGGL(vqc_kernel, dim3(grid), dim3(256), 0, stream,
                       x, w, fc_w, fc_b, out, Btot);
}

// Round 21
// 12.487 us; speedup vs baseline: 1.6780x; 1.6780x over previous
//
#include <hip/hip_runtime.h>

typedef float f2 __attribute__((ext_vector_type(2)));

#define N_QUBITS 5
#define DIM 32

// ---------- verified perm machinery (rounds 1/2/7-19) ----------
__host__ __device__ constexpr int cnot_apply(int i, int ctrl, int tgt) {
    const int pc = N_QUBITS - 1 - ctrl;
    const int pt = N_QUBITS - 1 - tgt;
    return i ^ (((i >> pc) & 1) << pt);
}
__host__ __device__ constexpr int layer_perm(int i, int r) {
    int idx = i;
    for (int q = N_QUBITS - 1; q >= 0; --q)
        idx = cnot_apply(idx, q, (q + r) % N_QUBITS);
    return idx;
}
__host__ __device__ constexpr int invP(int p, int r) {
    for (int l = 0; l < 32; ++l) if (layer_perm(l, r) == p) return l;
    return 0;
}
__host__ __device__ constexpr int pc5(int m) {
    int c = 0;
    for (int b = 0; b < 5; ++b) c += (m >> b) & 1;
    return c;
}
__host__ __device__ constexpr int pow3(int n) {
    int r = 1;
    for (int i = 0; i < n; ++i) r *= 3;
    return r;
}
__host__ __device__ constexpr int Mmask(int q) {
    int m = 0;
    for (int b = 0; b < 5; ++b)
        m |= ((invP(1 << b, 2) >> (4 - q)) & 1) << b;
    return m;
}
__host__ __device__ constexpr int NC(int q) { return pow3(pc5(Mmask(q))); }
__host__ __device__ constexpr int SB(int Q) {     // string-id base per qubit
    int s = 0;
    for (int q = 0; q < Q; ++q) s += NC(q);
    return s;
}
#define NS_TOTAL (SB(5))

// One Pauli string (r19 PASS-verified machinery, unchanged)
struct SInfo {
    int sign;
    int nf;
    int fidx[5];
    int k;
    int eb[5];
    int et[5];
};

__host__ __device__ constexpr SInfo make_sinfo(int Q, int C) {
    SInfo s{};
    const int M = Mmask(Q);
    int x = 0, z = 0, c = C;
    s.nf = 0;
    for (int b = 0; b < 5; ++b) {
        if ((M >> b) & 1) {
            const int t = c % 3; c /= 3;
            s.fidx[s.nf] = b * 3 + t;
            s.nf++;
            if (t == 0)      z |= 1 << b;
            else if (t == 1) x |= 1 << b;
            else           { x |= 1 << b; z |= 1 << b; }
        }
    }
    const int xp = layer_perm(x, 1);
    int zp = 0;
    for (int b = 0; b < 5; ++b)
        zp |= (pc5(z & invP(1 << b, 1)) & 1) << b;
    const int d  = pc5(x & z) - pc5(xp & zp);
    const int dm = ((d % 4) + 4) % 4;
    s.sign = (dm == 0) ? 1 : -1;
    s.k = 0;
    for (int b = 0; b < 5; ++b) {
        const int tx = (xp >> b) & 1, tz = (zp >> b) & 1;
        if (tx | tz) {
            s.eb[s.k] = b;
            s.et[s.k] = tx ? (tz ? 2 : 1) : 0;
            s.k++;
        }
    }
    return s;
}

#define EPICK(T, B) ((T) == 0 ? EZ[B] : ((T) == 1 ? EX[B] : EY[B]))

// Per-string term: E-product structure compile-time; uniform coefficient
// (sign * prod of a-values) read from LDS broadcast (precomputed in preamble).
template<int Q, int C>
__device__ __forceinline__ f2 sterm(const float* __restrict__ s_cf,
        const f2 (&EZ)[5], const f2 (&EX)[5], const f2 (&EY)[5]) {
    constexpr SInfo s = make_sinfo(Q, C);
    const float cf = s_cf[SB(Q) + C];       // compile-time LDS offset
    f2 e = EPICK(s.et[0], s.eb[0]);
    if constexpr (s.k > 1) e *= EPICK(s.et[1], s.eb[1]);
    if constexpr (s.k > 2) e *= EPICK(s.et[2], s.eb[2]);
    if constexpr (s.k > 3) e *= EPICK(s.et[3], s.eb[3]);
    if constexpr (s.k > 4) e *= EPICK(s.et[4], s.eb[4]);
    return e * cf;
}

// Balanced tree sum over C in [LO, LO+N): log-depth dependency chains.
template<int Q, int LO, int N>
struct TSum {
    static __device__ __forceinline__ f2 go(const float* __restrict__ s_cf,
            const f2 (&EZ)[5], const f2 (&EX)[5], const f2 (&EY)[5]) {
        if constexpr (N == 1) {
            return sterm<Q, LO>(s_cf, EZ, EX, EY);
        } else {
            return TSum<Q, LO, N / 2>::go(s_cf, EZ, EX, EY) +
                   TSum<Q, LO + N / 2, N - N / 2>::go(s_cf, EZ, EX, EY);
        }
    }
};

// Heisenberg picture, 2-batch packed f2 (r19 base, PASS @14.33us) with
// uniform string coefficients hoisted to LDS + tree-reassociated sums.
__global__ __launch_bounds__(256, 4) void vqc_kernel(
    const float* __restrict__ x,      // (B, 5)
    const float* __restrict__ w,      // (2, 5, 3)
    const float* __restrict__ fc_w,   // (8, 5)
    const float* __restrict__ fc_b,   // (8,)
    float* __restrict__ out,          // (B, 8)
    int Btot)
{
    __shared__ float s_g0[N_QUBITS][8];   // layer 0: full Rot coeffs (r15-verified)
    __shared__ float s_a[15];             // Heisenberg coefs (r19-verified)
    __shared__ float s_cf[NS_TOTAL];      // per-string uniform coefficients
    __shared__ float s_fc_w[40];
    __shared__ float s_fc_b[8];

    const int t = threadIdx.x;
    // ---- phase 1: gate coeffs + Heisenberg a + FC consts ----
    if (t < N_QUBITS) {
        const float phi = w[t * 3 + 0];
        const float th  = w[t * 3 + 1];
        const float om  = w[t * 3 + 2];
        float s, c;   sincosf(0.5f * th, &s, &c);
        float sp, cp; sincosf(0.5f * (phi + om), &sp, &cp);
        float sm, cm; sincosf(0.5f * (phi - om), &sm, &cm);
        s_g0[t][0] =  cp * c;  s_g0[t][1] = -sp * c;
        s_g0[t][2] = -cm * s;  s_g0[t][3] = -sm * s;
        s_g0[t][4] =  cm * s;  s_g0[t][5] = -sm * s;
        s_g0[t][6] =  cp * c;  s_g0[t][7] =  sp * c;
    } else if (t >= 8 && t < 13) {
        const int q = t - 8;
        const float phi = w[(N_QUBITS + q) * 3 + 0];
        const float th  = w[(N_QUBITS + q) * 3 + 1];
        float sth, cth; sincosf(th,  &sth, &cth);
        float sph, cph; sincosf(phi, &sph, &cph);
        const int b = 4 - q;
        s_a[b * 3 + 0] = cth;
        s_a[b * 3 + 1] = -sth * cph;
        s_a[b * 3 + 2] =  sth * sph;
    } else if (t >= 64 && t < 104) {
        s_fc_w[t - 64] = fc_w[t - 64];
    } else if (t >= 104 && t < 112) {
        s_fc_b[t - 104] = fc_b[t - 104];
    }
    __syncthreads();

    // ---- phase 2: per-string uniform coefficients (scalar, array-free) ----
    // Replicates make_sinfo's cf/sign formulas (r19-verified) in runtime form.
    if (t < NS_TOTAL) {
        int sid = t, Q = 0;
        while (Q < 4 && sid >= NC(Q)) { sid -= NC(Q); ++Q; }
        const int M = Mmask(Q);
        int xx = 0, zz = 0, c = sid;
        float cf = 1.f;
        for (int b = 0; b < 5; ++b) {
            if ((M >> b) & 1) {
                const int tt = c % 3; c /= 3;
                cf *= s_a[b * 3 + tt];
                if (tt == 0)      zz |= 1 << b;
                else if (tt == 1) xx |= 1 << b;
                else            { xx |= 1 << b; zz |= 1 << b; }
            }
        }
        const int xp = layer_perm(xx, 1);
        int zp = 0;
        for (int b = 0; b < 5; ++b)
            zp |= (pc5(zz & invP(1 << b, 1)) & 1) << b;
        const int d = pc5(xx & zz) - pc5(xp & zp);
        if ((((d % 4) + 4) % 4) != 0) cf = -cf;
        s_cf[t] = cf;
    }
    __syncthreads();

    const int b0 = blockIdx.x * 512 + t;
    if (b0 >= Btot) return;
    const int b1 = b0 + 256;
    const int b1c = (b1 < Btot) ? b1 : b0;        // clamp for loads only

    const float* xp0 = x + (size_t)b0 * 5;
    const float* xp1 = x + (size_t)b1c * 5;

    // ---- per-qubit v = Rot0_q RX(x_q)|0> and Pauli expectations (r19 verbatim) ----
    f2 EZ[5], EX[5], EY[5];
#pragma unroll
    for (int q = 0; q < N_QUBITS; ++q) {
        float s0, c0, s1, c1;
        __sincosf(0.5f * xp0[q], &s0, &c0);
        __sincosf(0.5f * xp1[q], &s1, &c1);
        const f2 cc = f2{c0, c1}, ss = f2{s0, s1};
        const f2 v0re = s_g0[q][0] * cc + s_g0[q][3] * ss;
        const f2 v0im = s_g0[q][1] * cc - s_g0[q][2] * ss;
        const f2 v1re = s_g0[q][4] * cc + s_g0[q][7] * ss;
        const f2 v1im = s_g0[q][5] * cc - s_g0[q][6] * ss;
        const int bb = 4 - q;
        EZ[bb] = v0re * v0re + v0im * v0im - v1re * v1re - v1im * v1im;
        EX[bb] = 2.f * (v0re * v1re + v0im * v1im);
        EY[bb] = 2.f * (v0re * v1im - v0im * v1re);
    }

    // ---- expvals: tree-summed compile-time Pauli strings, LDS coefs ----
    f2 ev[N_QUBITS];
    ev[0] = TSum<0, 0, NC(0)>::go(s_cf, EZ, EX, EY);
    ev[1] = TSum<1, 0, NC(1)>::go(s_cf, EZ, EX, EY);
    ev[2] = TSum<2, 0, NC(2)>::go(s_cf, EZ, EX, EY);
    ev[3] = TSum<3, 0, NC(3)>::go(s_cf, EZ, EX, EY);
    ev[4] = TSum<4, 0, NC(4)>::go(s_cf, EZ, EX, EY);

    // ---- FC (packed over both batches, r19 verbatim) ----
    f2 o[8];
#pragma unroll
    for (int j = 0; j < 8; ++j) {
        f2 acc = f2{s_fc_b[j], s_fc_b[j]};
#pragma unroll
        for (int q = 0; q < 5; ++q) acc += ev[q] * s_fc_w[j * 5 + q];
        o[j] = acc;
    }

    // ---- stores: two coalesced float4 pairs (r19 verbatim) ----
    float4* op0 = (float4*)(out + (size_t)b0 * 8);
    op0[0] = make_float4(o[0].x, o[1].x, o[2].x, o[3].x);
    op0[1] = make_float4(o[4].x, o[5].x, o[6].x, o[7].x);
    if (b1 < Btot) {
        float4* op1 = (float4*)(out + (size_t)b1 * 8);
        op1[0] = make_float4(o[0].y, o[1].y, o[2].y, o[3].y);
        op1[1] = make_float4(o[4].y, o[5].y, o[6].y, o[7].y);
    }
}

extern "C" void kernel_launch(void* const* d_in, const int* in_sizes, int n_in,
                              void* d_out, int out_size, void* d_ws, size_t ws_size,
                              hipStream_t stream) {
    const float* x    = (const float*)d_in[0];
    const float* w    = (const float*)d_in[1];
    const float* fc_w = (const float*)d_in[2];
    const float* fc_b = (const float*)d_in[3];
    float* out = (float*)d_out;

    const int Btot = in_sizes[0] / N_QUBITS;   // 262144
    const int grid = (Btot + 511) / 512;       // 2 batches per thread
    hipLaunchKernelGGL(vqc_kernel, dim3(grid), dim3(256), 0, stream,
                       x, w, fc_w, fc_b, out, Btot);
}